// Round 6
// baseline (218.621 us; speedup 1.0000x reference)
//
#include <hip/hip_runtime.h>
#include <hip/hip_bf16.h>

#define LAMBDA_INIT_F 0.35550906759096927f
#define ONE_MINUS_LI  0.64449093240903073f
#define QSCALE 0.36067376022224085f   // 0.25 * log2(e): exp(s) == exp2(s_scaled)

typedef unsigned short u16;
typedef unsigned int   u32;
typedef short s8v  __attribute__((ext_vector_type(8)));
typedef u32   u32x2 __attribute__((ext_vector_type(2)));
typedef u32   u32x4 __attribute__((ext_vector_type(4)));
typedef float f16v __attribute__((ext_vector_type(16)));

__device__ __forceinline__ u16 f2bf(float f) {
    __hip_bfloat16 h = __float2bfloat16(f);
    return *reinterpret_cast<u16*>(&h);
}
__device__ __forceinline__ u32 pk2bf(float lo, float hi) {
    return (u32)f2bf(lo) | ((u32)f2bf(hi) << 16);
}
union U4S8 { u32 u[4]; s8v s; };
__device__ __forceinline__ s8v mks8(u32 a, u32 b, u32 c, u32 d) {
    U4S8 x; x.u[0]=a; x.u[1]=b; x.u[2]=c; x.u[3]=d; return x.s;
}

// raw v_exp_f32 (1 inst) — libm exp2f is ~8 inst without -ffast-math
__device__ __forceinline__ float fexp2(float x) {
#if __has_builtin(__builtin_amdgcn_exp2f)
    return __builtin_amdgcn_exp2f(x);
#else
    float r; asm volatile("v_exp_f32 %0, %1\n\ts_nop 1" : "=v"(r) : "v"(x)); return r;
#endif
}

// gfx950 full-rate bf16 MFMA (K=16). C layout identical to 32x32x8_1k.
#define MFMA16(a,b,c) __builtin_amdgcn_mfma_f32_32x32x16_bf16((a),(b),(c),0,0,0)

// exchange halves across lane<32 / lane>=32
__device__ __forceinline__ void plswap2(u32& a, u32& b) {
    auto r = __builtin_amdgcn_permlane32_swap(a, b, false, false);
    a = r[0]; b = r[1];
}

// ---------------------------------------------------------------------------
// Kernel 0: prep. Blocks 0..79: transpose f32 weights -> bf16 WT[1280][256]
// (16 WT-rows per block). Blocks 80..143: x (f32) -> xbf (bf16), 64 rows each
// (float4 loads).
// ---------------------------------------------------------------------------
__global__ __launch_bounds__(256) void prep_kernel(
    const float* __restrict__ Wq, const float* __restrict__ Wkv,
    const float* __restrict__ Wg, const float* __restrict__ Wout,
    const float* __restrict__ x,
    u16* __restrict__ WT, u16* __restrict__ xbf)
{
    const int bid = blockIdx.x;
    const int tid = threadIdx.x;

    if (bid >= 80) {               // x convert: rows (bid-80)*64 .. +63
        const int r0 = (bid - 80) * 64;
        const float4* src = (const float4*)(x + (size_t)r0 * 256);
        u32* dst = (u32*)(xbf + (size_t)r0 * 256);
        for (int idx = tid; idx < 64 * 64; idx += 256) {
            float4 v = src[idx];
            dst[2*idx + 0] = pk2bf(v.x, v.y);
            dst[2*idx + 1] = pk2bf(v.z, v.w);
        }
        return;
    }

    __shared__ u16 tile[16 * 258];
    const int n0g = bid * 16;      // WT row base (0..1279)
    const float* src; int cols; int ncol0;
    if      (n0g < 256)  { src = Wq;   cols = 256; ncol0 = n0g; }
    else if (n0g < 768)  { src = Wkv;  cols = 512; ncol0 = n0g - 256; }
    else if (n0g < 1024) { src = Wg;   cols = 256; ncol0 = n0g - 768; }
    else                 { src = Wout; cols = 256; ncol0 = n0g - 1024; }

    const float* srow = src + (size_t)tid * cols + ncol0;
#pragma unroll
    for (int j = 0; j < 8; ++j) {
        const float2 v = *(const float2*)(srow + 2*j);
        tile[(2*j + 0) * 258 + tid] = f2bf(v.x);
        tile[(2*j + 1) * 258 + tid] = f2bf(v.y);
    }
    __syncthreads();

    const u32* t32 = (const u32*)tile;           // row stride 129 u32
    const int nn = tid >> 4, part = tid & 15;
    u32* dst = (u32*)WT + (size_t)(n0g + nn) * 128 + part * 8;
    const u32* s2 = t32 + nn * 129 + part * 8;
#pragma unroll
    for (int j = 0; j < 8; ++j) dst[j] = s2[j];
}

// ---------------------------------------------------------------------------
// Kernel 1: MFMA projections. C[4096,1024] = xbf @ [Wq|Wk|Wv|Wg]; epilogue
// scatters to Qb (pre-scaled), Kb, Vb^T (bf16), Gb (f32 sigmoid).
// Grid 1024 = 64 mt x 16 nt, 256 thr, wave w -> (m-sub = w&1, n-sub = w>>1),
// 32x32 output per wave, full K=256 (R5 structure, −1.7us vs R1).
// V is stored TRANSPOSED: Vb[b][hv][d][i] — each register group r>>2 holds 4
// consecutive i at fixed d, packed into one 8-byte store (16x2B -> 8x8B),
// so attn can stage V with ds_write_b64 instead of a 16x b16 transpose.
// ---------------------------------------------------------------------------
__global__ __launch_bounds__(256) void proj_kernel(
    const u16* __restrict__ x, const u16* __restrict__ WT,
    const float* __restrict__ bg,
    u16* __restrict__ Qb, u16* __restrict__ Kb,
    u16* __restrict__ Vb, float* __restrict__ Gb)
{
    const int bid = blockIdx.x;
    const int nt = bid & 15, mt = bid >> 4;
    const int tid = threadIdx.x, w = tid >> 6, lane = tid & 63;
    const int l31 = lane & 31, hh = lane >> 5;
    const int ms = w & 1, nsub = w >> 1;
    const int m0 = mt * 64 + ms * 32;
    const int n0 = nt * 64 + nsub * 32;

    const u16* xr = x  + (size_t)(m0 + l31) * 256 + 8*hh;
    const u16* br = WT + (size_t)(n0 + l31) * 256 + 8*hh;

    f16v a0;
#pragma unroll
    for (int r = 0; r < 16; ++r) a0[r] = 0.f;

#pragma unroll
    for (int ks = 0; ks < 16; ++ks) {
        s8v xa = *(const s8v*)(xr + ks*16);
        s8v w0 = *(const s8v*)(br + ks*16);
        a0 = MFMA16(xa, w0, a0);
    }

    const int cat = nt >> 2;    // 0=Q 1=K 2=V^T 3=G
    const int n = n0 + l31;
    if (cat == 2) {
        const int nv = n - 512, hv = nv >> 5, d2 = nv & 31;
#pragma unroll
        for (int g = 0; g < 4; ++g) {
            const int R0 = m0 + 8*g + 4*hh;          // 4 consecutive rows R0..R0+3
            const int b = R0 >> 11, i = R0 & 2047;   // i % 4 == 0
            u32x2 vv;
            vv[0] = pk2bf(a0[4*g + 0], a0[4*g + 1]);
            vv[1] = pk2bf(a0[4*g + 2], a0[4*g + 3]);
            *reinterpret_cast<u32x2*>(
                (u32*)Vb + ((size_t)(b*8 + hv) * 32 + d2) * 1024 + (i >> 1)) = vv;
        }
    } else {
#pragma unroll
        for (int r = 0; r < 16; ++r) {
            const int il = (r & 3) + 8*(r >> 2) + 4*hh;
            const int R = m0 + il;
            const int b = R >> 11, i = R & 2047;
            const float v = a0[r];
            if (cat == 0) {
                const int h = n >> 4, d = n & 15;
                Qb[((size_t)(b*16 + h) * 2048 + i) * 16 + d] = f2bf(v * QSCALE);
            } else if (cat == 1) {
                const int nk = n - 256, h = nk >> 4, d = nk & 15;
                Kb[((size_t)(b*16 + h) * 2048 + i) * 16 + d] = f2bf(v);
            } else {
                const int gcol = n - 768;
                const float t = v + bg[gcol];
                Gb[(size_t)R * 256 + gcol] = 1.0f / (1.0f + __expf(-t));
            }
        }
    }
}

// ---------------------------------------------------------------------------
// Kernel 2: MFMA flash differential attention + LN + gate -> bf16 A.
// Grid 1024, 512 thr = 8 waves = (jq = w>>1, s = w&1). S^T = MFMA16(A=K,B=Q);
// PV A-frags via permlane32_swap redistribution. V arrives TRANSPOSED from
// proj ([d][i] rows), so staging = 2x ds_write_b64 per thread-round (was 16x
// ds_write_b16 + unpack). V LDS tile [d][j], row stride 18 u32 (2-way bank
// alias = free; b64-aligned every row). Slot = K 576 + V 576 = 1152 u32;
// 2 buf x 4 slots = 9216 u32 = 36.9 KB -> 4 blocks/CU (147 KB LDS/CU).
// ---------------------------------------------------------------------------
__global__ __launch_bounds__(512, 8) void attn_kernel(
    const u16* __restrict__ Q, const u16* __restrict__ K,
    const u16* __restrict__ V, const float* __restrict__ G,
    const float* __restrict__ lq1, const float* __restrict__ lk1,
    const float* __restrict__ lq2, const float* __restrict__ lk2,
    const float* __restrict__ gamma, const float* __restrict__ beta,
    u16* __restrict__ A)
{
    // staging: 2 buf x 4 slots x 1152 u32 = 9216 u32 = 36.9 KB
    // combine (reuse): 8 x (32x33 f32) O + 8x32 f32 l = 8704 f32
    __shared__ float smemf[9216];
    u32* stu = (u32*)smemf;

    const int bid = blockIdx.x;
    const int itile = bid & 63;
    const int combo = bid >> 6;
    const int ho = combo & 7, b = combo >> 3;
    const int i0 = itile * 32;

    const int tid = threadIdx.x, w = tid >> 6, lane = tid & 63;
    const int l31 = lane & 31, hh = lane >> 5;
    const int s = w & 1, jq = w >> 1;

    const u16* Qg = Q + ((size_t)(b*16 + 2*ho + s) * 2048 + (i0 + l31)) * 16;
    const s8v qf = *(const s8v*)(Qg + 8*hh);       // B-frag: col=query l31, k=8hh+e

    // --- staging assignment: wave-pair qp stages slot qp ---
    const int qp = tid >> 7;              // slot 0..3 (chunks qp*16 + t)
    const int pid = tid & 127;
    // K: 2 subheads x 32 rows x 8 u32 (pad 9); thread -> (ksub, krow, kseg)
    const int ksub = pid >> 6, krow = (pid >> 1) & 31, kseg = pid & 1;
    const u32* kgp = (const u32*)(K + (size_t)(b*16 + 2*ho + ksub) * 2048 * 16)
                     + (size_t)qp * 4096 + krow * 8 + kseg * 4;
    // V^T: 32 d-rows x 1024 u32; thread -> (vd = pid>>2, jseg = pid&3): 4 u32
    const int vd = pid >> 2, jseg = pid & 3;
    const u32* vgp = (const u32*)V + (size_t)(b*8 + ho) * 32768
                     + vd * 1024 + qp * 256 + jseg * 4;

    // LDS offsets (u32): slot base qp*1152; K at 0..575, V at 576..1151
    const int kw_off = qp*1152 + ksub*288 + krow*9 + kseg*4;   // u32 write
    const int vw_off = qp*1152 + 576 + vd*18 + jseg*4;         // u32 write (2xb64)
    const int kr_off = jq*1152 + s*288 + l31*9 + 4*hh;         // u32 read (k=8hh..+7)
    const int vr_off = jq*1152 + 576 + l31*18;                 // u32 read, +4hh+e

    f16v oacc;
#pragma unroll
    for (int r = 0; r < 16; ++r) oacc[r] = 0.f;
    float la0 = 0.f, la1 = 0.f;

    {   // prologue: stage round 0 into buffer 0
        u32 k0 = kgp[0], k1 = kgp[1], k2 = kgp[2], k3 = kgp[3];
        u32 v0 = vgp[0], v1 = vgp[1], v2 = vgp[2], v3 = vgp[3];
        u32* kd = stu + kw_off;
        kd[0]=k0; kd[1]=k1; kd[2]=k2; kd[3]=k3;
        u32* vdst = stu + vw_off;
        u32x2 va; va[0]=v0; va[1]=v1;
        u32x2 vb2w; vb2w[0]=v2; vb2w[1]=v3;
        *reinterpret_cast<u32x2*>(vdst) = va;
        *reinterpret_cast<u32x2*>(vdst + 2) = vb2w;
    }

    for (int t = 0; t < 16; ++t) {
        __syncthreads();
        const int p = t & 1, pn = 1 - p;
        const int tt = (t + 1) & 15;          // branchless wrap

        const u32* kp = kgp + (size_t)tt * 256;
        u32 nk0=kp[0], nk1=kp[1], nk2=kp[2], nk3=kp[3];
        const u32* vp = vgp + (size_t)tt * 16;
        u32 nv0=vp[0], nv1=vp[1], nv2=vp[2], nv3=vp[3];

        const u32* kb2 = stu + p*4608 + kr_off;
        const u32* vb2 = stu + p*4608 + vr_off;

        f16v sc;
#pragma unroll
        for (int r = 0; r < 16; ++r) sc[r] = 0.f;
        {
            s8v kf = mks8(kb2[0], kb2[1], kb2[2], kb2[3]);
            sc = MFMA16(kf, qf, sc);
        }
        float pv[16];
#pragma unroll
        for (int r = 0; r < 16; ++r) pv[r] = fexp2(sc[r]);
        la0 += pv[0];  la0 += pv[1];  la0 += pv[2];  la0 += pv[3];
        la1 += pv[4];  la1 += pv[5];  la1 += pv[6];  la1 += pv[7];
        la0 += pv[8];  la0 += pv[9];  la0 += pv[10]; la0 += pv[11];
        la1 += pv[12]; la1 += pv[13]; la1 += pv[14]; la1 += pv[15];

        // pack truncated bf16 pairs: w_i = keys (2i, 2i+1) + 4hh offset pattern
        u32 wv[8];
#pragma unroll
        for (int i = 0; i < 8; ++i)
            wv[i] = __builtin_amdgcn_perm(__float_as_uint(pv[2*i+1]),
                                          __float_as_uint(pv[2*i+0]), 0x07060302);
        // redistribute across wave halves for K=16 A-frags
        plswap2(wv[0], wv[2]); plswap2(wv[1], wv[3]);
        {
            s8v pf0 = mks8(wv[0], wv[1], wv[2], wv[3]);
            s8v vf0 = mks8(vb2[4*hh+0], vb2[4*hh+1], vb2[4*hh+2], vb2[4*hh+3]);
            oacc = MFMA16(pf0, vf0, oacc);
        }
        plswap2(wv[4], wv[6]); plswap2(wv[5], wv[7]);
        {
            s8v pf1 = mks8(wv[4], wv[5], wv[6], wv[7]);
            s8v vf1 = mks8(vb2[8+4*hh+0], vb2[8+4*hh+1], vb2[8+4*hh+2], vb2[8+4*hh+3]);
            oacc = MFMA16(pf1, vf1, oacc);
        }

        {   // stage round tt into buffer pn
            u32* kd = stu + pn*4608 + kw_off;
            kd[0]=nk0; kd[1]=nk1; kd[2]=nk2; kd[3]=nk3;
            u32* vdst = stu + pn*4608 + vw_off;
            u32x2 va; va[0]=nv0; va[1]=nv1;
            u32x2 vb2w; vb2w[0]=nv2; vb2w[1]=nv3;
            *reinterpret_cast<u32x2*>(vdst) = va;
            *reinterpret_cast<u32x2*>(vdst + 2) = vb2w;
        }
    }
    const float lacc = la0 + la1;

    __syncthreads();                  // staging dead; reuse LDS for combine
    float ltot = lacc + __shfl_xor(lacc, 32);
    float* ob = smemf + w * 1056;
#pragma unroll
    for (int r = 0; r < 16; ++r) {
        const int il = (r & 3) + 8*(r >> 2) + 4*hh;   // local query row
        ob[il*33 + l31] = oacc[r];                    // col = d = l31
    }
    if (lane < 32) smemf[8448 + w*32 + l31] = ltot;
    __syncthreads();

    if (tid < 128) {
        const int ii = tid >> 2, sub = tid & 3, d0 = sub * 8;
        float l1 = 0.f, l2 = 0.f;
#pragma unroll
        for (int q = 0; q < 4; ++q) {
            l1 += smemf[8448 + (2*q + 0)*32 + ii];
            l2 += smemf[8448 + (2*q + 1)*32 + ii];
        }

        float sA = 0.f, sB = 0.f;
#pragma unroll
        for (int d = 0; d < 16; ++d) {
            sA += lq1[d] * lk1[d];
            sB += lq2[d] * lk2[d];
        }
        const float lam = __expf(sA) - __expf(sB) + LAMBDA_INIT_F;
        const float c1 = 1.f / l1, c2 = lam / l2;

        float od[8]; float mu = 0.f;
#pragma unroll
        for (int dd = 0; dd < 8; ++dd) {
            const int d = d0 + dd;
            float o1 = 0.f, o2 = 0.f;
#pragma unroll
            for (int q = 0; q < 4; ++q) {
                o1 += smemf[(2*q + 0)*1056 + ii*33 + d];
                o2 += smemf[(2*q + 1)*1056 + ii*33 + d];
            }
            od[dd] = o1 * c1 - o2 * c2;
            mu += od[dd];
        }
        mu += __shfl_xor(mu, 1); mu += __shfl_xor(mu, 2);
        mu *= (1.f / 32.f);
        float var = 0.f;
#pragma unroll
        for (int dd = 0; dd < 8; ++dd) { const float t2 = od[dd] - mu; var += t2 * t2; }
        var += __shfl_xor(var, 1); var += __shfl_xor(var, 2);
        var *= (1.f / 32.f);
        const float rs = rsqrtf(var + 1e-5f);

        const int R = b*2048 + i0 + ii;
        const float* Gr = G + (size_t)R * 256 + ho*32 + d0;
        const float4 g0 = *(const float4*)(Gr);
        const float4 g1 = *(const float4*)(Gr + 4);
        const float gg[8] = { g0.x, g0.y, g0.z, g0.w, g1.x, g1.y, g1.z, g1.w };
        float vals[8];
#pragma unroll
        for (int dd = 0; dd < 8; ++dd) {
            const float val = (od[dd] - mu)*rs*gamma[d0 + dd] + beta[d0 + dd];
            vals[dd] = val * ONE_MINUS_LI * gg[dd];
        }
        u32x4 pk;
        pk[0] = pk2bf(vals[0], vals[1]);
        pk[1] = pk2bf(vals[2], vals[3]);
        pk[2] = pk2bf(vals[4], vals[5]);
        pk[3] = pk2bf(vals[6], vals[7]);
        *reinterpret_cast<u32x4*>(A + (size_t)R * 256 + ho*32 + d0) = pk;
    }
}

// ---------------------------------------------------------------------------
// Kernel 3: out = A(bf16) @ Wout + bout -> f32. Grid 256, 512 threads:
// 8 waves = 4 (32x32) tiles x 2 K-halves; LDS combine of the K-split.
// ---------------------------------------------------------------------------
__global__ __launch_bounds__(512) void out_kernel(
    const u16* __restrict__ Abf, const u16* __restrict__ WT,
    const float* __restrict__ bout, float* __restrict__ out)
{
    __shared__ float cs[4][32 * 33];

    const int bid = blockIdx.x;
    const int nt = bid & 3, mt = bid >> 2;
    const int tid = threadIdx.x, w = tid >> 6, lane = tid & 63;
    const int l31 = lane & 31, hh = lane >> 5;
    const int t = w >> 1, kh = w & 1;
    const int m0 = mt * 64 + (t & 1) * 32;
    const int n0 = nt * 64 + (t >> 1) * 32;

    const u16* ar = Abf + (size_t)(m0 + l31) * 256 + kh*128 + 8*hh;
    const u16* br = WT + (size_t)(1024 + n0 + l31) * 256 + kh*128 + 8*hh;

    f16v acc;
#pragma unroll
    for (int r = 0; r < 16; ++r) acc[r] = 0.f;

#pragma unroll
    for (int ks = 0; ks < 8; ++ks) {
        s8v aa = *(const s8v*)(ar + ks*16);
        s8v ba = *(const s8v*)(br + ks*16);
        acc = MFMA16(aa, ba, acc);
    }

    if (kh == 0) {
#pragma unroll
        for (int r = 0; r < 16; ++r) {
            const int il = (r & 3) + 8*(r >> 2) + 4*hh;
            cs[t][il*33 + l31] = acc[r];
        }
    }
    __syncthreads();
    if (kh == 1) {
        const float bv = bout[n0 + l31];
#pragma unroll
        for (int r = 0; r < 16; ++r) {
            const int il = (r & 3) + 8*(r >> 2) + 4*hh;
            const int m = m0 + il;
            out[(size_t)m * 256 + n0 + l31] = acc[r] + cs[t][il*33 + l31] + bv;
        }
    }
}

// ---------------------------------------------------------------------------
extern "C" void kernel_launch(void* const* d_in, const int* in_sizes, int n_in,
                              void* d_out, int out_size, void* d_ws, size_t ws_size,
                              hipStream_t stream) {
    const float* x    = (const float*)d_in[0];
    const float* Wq   = (const float*)d_in[1];
    const float* Wkv  = (const float*)d_in[2];
    const float* Wout = (const float*)d_in[3];
    const float* bout = (const float*)d_in[4];
    const float* Wg   = (const float*)d_in[5];
    const float* bg   = (const float*)d_in[6];
    const float* lq1  = (const float*)d_in[7];
    const float* lk1  = (const float*)d_in[8];
    const float* lq2  = (const float*)d_in[9];
    const float* lk2  = (const float*)d_in[10];
    const float* lng  = (const float*)d_in[11];
    const float* lnb  = (const float*)d_in[12];

    // ws: WT[1280*256] | xbf | Qb | Kb | Vb^T (u16) | Gb (f32) | Abf (u16)
    u16*   WT  = (u16*)d_ws;
    u16*   xbf = WT + 327680;
    u16*   Qb  = xbf + 1048576;
    u16*   Kb  = Qb + 1048576;
    u16*   Vb  = Kb + 1048576;
    float* Gb  = (float*)(Vb + 1048576);
    u16*   Abf = (u16*)(Gb + 1048576);

    hipLaunchKernelGGL(prep_kernel, dim3(144), dim3(256), 0, stream,
                       Wq, Wkv, Wg, Wout, x, WT, xbf);
    hipLaunchKernelGGL(proj_kernel, dim3(1024), dim3(256), 0, stream,
                       xbf, WT, bg, Qb, Kb, Vb, Gb);
    hipLaunchKernelGGL(attn_kernel, dim3(1024), dim3(512), 0, stream,
                       Qb, Kb, Vb, Gb, lq1, lk1, lq2, lk2, lng, lnb, Abf);
    hipLaunchKernelGGL(out_kernel, dim3(256), dim3(512), 0, stream,
                       Abf, WT, bout, (float*)d_out);
}

// Round 7
// 142.442 us; speedup vs baseline: 1.5348x; 1.5348x over previous
//
#include <hip/hip_runtime.h>
#include <hip/hip_bf16.h>

#define LAMBDA_INIT_F 0.35550906759096927f
#define ONE_MINUS_LI  0.64449093240903073f
#define QSCALE 0.36067376022224085f   // 0.25 * log2(e): exp(s) == exp2(s_scaled)

typedef unsigned short u16;
typedef unsigned int   u32;
typedef short s8v  __attribute__((ext_vector_type(8)));
typedef u32   u32x4 __attribute__((ext_vector_type(4)));
typedef float f16v __attribute__((ext_vector_type(16)));

__device__ __forceinline__ u16 f2bf(float f) {
    __hip_bfloat16 h = __float2bfloat16(f);
    return *reinterpret_cast<u16*>(&h);
}
__device__ __forceinline__ u32 pk2bf(float lo, float hi) {
    return (u32)f2bf(lo) | ((u32)f2bf(hi) << 16);
}
union U4S8 { u32 u[4]; s8v s; };
__device__ __forceinline__ s8v mks8(u32 a, u32 b, u32 c, u32 d) {
    U4S8 x; x.u[0]=a; x.u[1]=b; x.u[2]=c; x.u[3]=d; return x.s;
}

// raw v_exp_f32 (1 inst) — libm exp2f is ~8 inst without -ffast-math
__device__ __forceinline__ float fexp2(float x) {
#if __has_builtin(__builtin_amdgcn_exp2f)
    return __builtin_amdgcn_exp2f(x);
#else
    float r; asm volatile("v_exp_f32 %0, %1\n\ts_nop 1" : "=v"(r) : "v"(x)); return r;
#endif
}

// gfx950 full-rate bf16 MFMA (K=16). C layout identical to 32x32x8_1k.
#define MFMA16(a,b,c) __builtin_amdgcn_mfma_f32_32x32x16_bf16((a),(b),(c),0,0,0)

// exchange halves across lane<32 / lane>=32
__device__ __forceinline__ void plswap2(u32& a, u32& b) {
    auto r = __builtin_amdgcn_permlane32_swap(a, b, false, false);
    a = r[0]; b = r[1];
}

// XCD-aware bijective swizzle for grid 1024 (8 XCDs, 128 blocks each):
// HW assigns bid%8 -> XCD; logical work L = (bid&7)*128 + bid>>3 gives each
// XCD a CONTIGUOUS logical range -> L2-local K/V heads / row panels.
__device__ __forceinline__ int xcd_swz1024(int bid) {
    return (bid & 7) * 128 + (bid >> 3);
}

// ---------------------------------------------------------------------------
// Kernel 0: prep. Blocks 0..79: transpose f32 weights -> bf16 WT[1280][256]
// (16 WT-rows per block). Blocks 80..143: x (f32) -> xbf (bf16), 64 rows each
// (float4 loads).
// ---------------------------------------------------------------------------
__global__ __launch_bounds__(256) void prep_kernel(
    const float* __restrict__ Wq, const float* __restrict__ Wkv,
    const float* __restrict__ Wg, const float* __restrict__ Wout,
    const float* __restrict__ x,
    u16* __restrict__ WT, u16* __restrict__ xbf)
{
    const int bid = blockIdx.x;
    const int tid = threadIdx.x;

    if (bid >= 80) {               // x convert: rows (bid-80)*64 .. +63
        const int r0 = (bid - 80) * 64;
        const float4* src = (const float4*)(x + (size_t)r0 * 256);
        u32* dst = (u32*)(xbf + (size_t)r0 * 256);
        for (int idx = tid; idx < 64 * 64; idx += 256) {
            float4 v = src[idx];
            dst[2*idx + 0] = pk2bf(v.x, v.y);
            dst[2*idx + 1] = pk2bf(v.z, v.w);
        }
        return;
    }

    __shared__ u16 tile[16 * 258];
    const int n0g = bid * 16;      // WT row base (0..1279)
    const float* src; int cols; int ncol0;
    if      (n0g < 256)  { src = Wq;   cols = 256; ncol0 = n0g; }
    else if (n0g < 768)  { src = Wkv;  cols = 512; ncol0 = n0g - 256; }
    else if (n0g < 1024) { src = Wg;   cols = 256; ncol0 = n0g - 768; }
    else                 { src = Wout; cols = 256; ncol0 = n0g - 1024; }

    const float* srow = src + (size_t)tid * cols + ncol0;
#pragma unroll
    for (int j = 0; j < 8; ++j) {
        const float2 v = *(const float2*)(srow + 2*j);
        tile[(2*j + 0) * 258 + tid] = f2bf(v.x);
        tile[(2*j + 1) * 258 + tid] = f2bf(v.y);
    }
    __syncthreads();

    const u32* t32 = (const u32*)tile;           // row stride 129 u32
    const int nn = tid >> 4, part = tid & 15;
    u32* dst = (u32*)WT + (size_t)(n0g + nn) * 128 + part * 8;
    const u32* s2 = t32 + nn * 129 + part * 8;
#pragma unroll
    for (int j = 0; j < 8; ++j) dst[j] = s2[j];
}

// ---------------------------------------------------------------------------
// Kernel 1: MFMA projections (R5 structure). C[4096,1024] = xbf @ W cat;
// grid 1024 = 64 mt x 16 nt (XCD-swizzled: each XCD owns 8 contiguous mt
// panels), 256 thr, wave w -> (m-sub = w&1, n-sub = w>>1), 32x32 per wave.
// ---------------------------------------------------------------------------
__global__ __launch_bounds__(256) void proj_kernel(
    const u16* __restrict__ x, const u16* __restrict__ WT,
    const float* __restrict__ bg,
    u16* __restrict__ Qb, u16* __restrict__ Kb,
    u16* __restrict__ Vb, float* __restrict__ Gb)
{
    const int bidl = xcd_swz1024(blockIdx.x);
    const int nt = bidl & 15, mt = bidl >> 4;
    const int tid = threadIdx.x, w = tid >> 6, lane = tid & 63;
    const int l31 = lane & 31, hh = lane >> 5;
    const int ms = w & 1, nsub = w >> 1;
    const int m0 = mt * 64 + ms * 32;
    const int n0 = nt * 64 + nsub * 32;

    const u16* xr = x  + (size_t)(m0 + l31) * 256 + 8*hh;
    const u16* br = WT + (size_t)(n0 + l31) * 256 + 8*hh;

    f16v a0;
#pragma unroll
    for (int r = 0; r < 16; ++r) a0[r] = 0.f;

#pragma unroll
    for (int ks = 0; ks < 16; ++ks) {
        s8v xa = *(const s8v*)(xr + ks*16);
        s8v w0 = *(const s8v*)(br + ks*16);
        a0 = MFMA16(xa, w0, a0);
    }

    const int cat = nt >> 2;    // 0=Q 1=K 2=V 3=G
    const int n = n0 + l31;
#pragma unroll
    for (int r = 0; r < 16; ++r) {
        const int il = (r & 3) + 8*(r >> 2) + 4*hh;
        const int R = m0 + il;
        const int b = R >> 11, i = R & 2047;
        const float v = a0[r];
        if (cat == 0) {
            const int h = n >> 4, d = n & 15;
            Qb[((size_t)(b*16 + h) * 2048 + i) * 16 + d] = f2bf(v * QSCALE);
        } else if (cat == 1) {
            const int nk = n - 256, h = nk >> 4, d = nk & 15;
            Kb[((size_t)(b*16 + h) * 2048 + i) * 16 + d] = f2bf(v);
        } else if (cat == 2) {
            const int nv = n - 512, hv = nv >> 5, d2 = nv & 31;
            Vb[((size_t)(b*8 + hv) * 2048 + i) * 32 + d2] = f2bf(v);
        } else {
            const int gcol = n - 768;
            const float t = v + bg[gcol];
            Gb[(size_t)R * 256 + gcol] = 1.0f / (1.0f + __expf(-t));
        }
    }
}

// ---------------------------------------------------------------------------
// Kernel 2: MFMA flash differential attention + LN + gate -> bf16 A.
// EXACT R5 structure (verified 139.8us config) + XCD swizzle: the 64 i-tile
// blocks of each (b,ho) head land on ONE XCD (2 combos/XCD) so the 256-KB
// K/V head is fetched into one L2 instead of all eight.
// ---------------------------------------------------------------------------
__global__ __launch_bounds__(512, 8) void attn_kernel(
    const u16* __restrict__ Q, const u16* __restrict__ K,
    const u16* __restrict__ V, const float* __restrict__ G,
    const float* __restrict__ lq1, const float* __restrict__ lk1,
    const float* __restrict__ lq2, const float* __restrict__ lk2,
    const float* __restrict__ gamma, const float* __restrict__ beta,
    u16* __restrict__ A)
{
    // staging: 2 buf x 4 slots x 1120 u32 = 8960 u32 = 35.8 KB
    // combine (reuse): 8 x (32x33 f32) O + 8x32 f32 l = 8704 f32
    __shared__ float smemf[8960];
    u16* st  = (u16*)smemf;
    u32* stu = (u32*)smemf;

    const int bidl = xcd_swz1024(blockIdx.x);
    const int itile = bidl & 63;
    const int combo = bidl >> 6;
    const int ho = combo & 7, b = combo >> 3;
    const int i0 = itile * 32;

    const int tid = threadIdx.x, w = tid >> 6, lane = tid & 63;
    const int l31 = lane & 31, hh = lane >> 5;
    const int s = w & 1, jq = w >> 1;

    const u16* Vg = V + (size_t)(b*8 + ho) * 2048 * 32;
    const u16* Qg = Q + ((size_t)(b*16 + 2*ho + s) * 2048 + (i0 + l31)) * 16;
    const s8v qf = *(const s8v*)(Qg + 8*hh);       // B-frag: col=query l31, k=8hh+e

    // --- staging assignment: wave-pair qp stages slot qp ---
    const int qp = tid >> 7;              // slot 0..3 (chunks qp*16 + t)
    const int pid = tid & 127;
    // K: 2 subheads x 32 rows x 8 u32; thread -> (ksub, krow, kseg): 4 u32
    const int ksub = pid >> 6, krow = (pid >> 1) & 31, kseg = pid & 1;
    const u32* kgp = (const u32*)(K + (size_t)(b*16 + 2*ho + ksub) * 2048 * 16)
                     + (size_t)qp * 4096 + krow * 8 + kseg * 4;
    // V: 32 rows(j) x 16 u32; thread -> (vj, vseg): 4 u32 = d vseg*8..+7
    const int vj = pid >> 2, vseg = pid & 3;
    const u32* vgp = (const u32*)Vg + (size_t)qp * 8192 + vj * 16 + vseg * 4;

    // LDS offsets: slot base qp*1120 u32 / qp*2240 u16; buffer +p*4480/+p*8960
    const int kw_off = qp*1120 + ksub*288 + krow*9 + kseg*4;   // u32 write
    const int vw_u16 = qp*2240 + 1152 + vj;                    // u16 write, +d*34
    const int vd0 = vseg * 8;
    const int kr_off = jq*1120 + s*288 + l31*9 + 4*hh;         // u32 read (k=8hh..+7)
    const int vr_off = jq*1120 + 576 + l31*17;                 // u32 read, +8f2+4hh

    f16v oacc;
#pragma unroll
    for (int r = 0; r < 16; ++r) oacc[r] = 0.f;
    float la0 = 0.f, la1 = 0.f;

    {   // prologue: stage round 0 into buffer 0
        u32 k0 = kgp[0], k1 = kgp[1], k2 = kgp[2], k3 = kgp[3];
        u32 v0 = vgp[0], v1 = vgp[1], v2 = vgp[2], v3 = vgp[3];
        u32* kd = stu + kw_off;
        kd[0]=k0; kd[1]=k1; kd[2]=k2; kd[3]=k3;
        u16* vd = st + vw_u16;
        vd[(vd0+0)*34] = (u16)(v0 & 0xffff); vd[(vd0+1)*34] = (u16)(v0 >> 16);
        vd[(vd0+2)*34] = (u16)(v1 & 0xffff); vd[(vd0+3)*34] = (u16)(v1 >> 16);
        vd[(vd0+4)*34] = (u16)(v2 & 0xffff); vd[(vd0+5)*34] = (u16)(v2 >> 16);
        vd[(vd0+6)*34] = (u16)(v3 & 0xffff); vd[(vd0+7)*34] = (u16)(v3 >> 16);
    }

    for (int t = 0; t < 16; ++t) {
        __syncthreads();
        const int p = t & 1, pn = 1 - p;
        const int tt = (t + 1) & 15;          // branchless wrap

        const u32* kp = kgp + (size_t)tt * 256;
        u32 nk0=kp[0], nk1=kp[1], nk2=kp[2], nk3=kp[3];
        const u32* vp = vgp + (size_t)tt * 512;
        u32 nv0=vp[0], nv1=vp[1], nv2=vp[2], nv3=vp[3];

        const u32* kb2 = stu + p*4480 + kr_off;
        const u32* vb2 = stu + p*4480 + vr_off;

        f16v sc;
#pragma unroll
        for (int r = 0; r < 16; ++r) sc[r] = 0.f;
        {
            s8v kf = mks8(kb2[0], kb2[1], kb2[2], kb2[3]);
            sc = MFMA16(kf, qf, sc);
        }
        float pv[16];
#pragma unroll
        for (int r = 0; r < 16; ++r) pv[r] = fexp2(sc[r]);
        la0 += pv[0];  la0 += pv[1];  la0 += pv[2];  la0 += pv[3];
        la1 += pv[4];  la1 += pv[5];  la1 += pv[6];  la1 += pv[7];
        la0 += pv[8];  la0 += pv[9];  la0 += pv[10]; la0 += pv[11];
        la1 += pv[12]; la1 += pv[13]; la1 += pv[14]; la1 += pv[15];

        // pack truncated bf16 pairs: w_i = keys (2i, 2i+1) + 4hh offset pattern
        u32 wv[8];
#pragma unroll
        for (int i = 0; i < 8; ++i)
            wv[i] = __builtin_amdgcn_perm(__float_as_uint(pv[2*i+1]),
                                          __float_as_uint(pv[2*i+0]), 0x07060302);
        // redistribute across wave halves for K=16 A-frags
        plswap2(wv[0], wv[2]); plswap2(wv[1], wv[3]);
        {
            s8v pf0 = mks8(wv[0], wv[1], wv[2], wv[3]);
            s8v vf0 = mks8(vb2[4*hh+0], vb2[4*hh+1], vb2[4*hh+2], vb2[4*hh+3]);
            oacc = MFMA16(pf0, vf0, oacc);
        }
        plswap2(wv[4], wv[6]); plswap2(wv[5], wv[7]);
        {
            s8v pf1 = mks8(wv[4], wv[5], wv[6], wv[7]);
            s8v vf1 = mks8(vb2[8+4*hh+0], vb2[8+4*hh+1], vb2[8+4*hh+2], vb2[8+4*hh+3]);
            oacc = MFMA16(pf1, vf1, oacc);
        }

        {   // stage round tt into buffer pn
            u32* kd = stu + pn*4480 + kw_off;
            kd[0]=nk0; kd[1]=nk1; kd[2]=nk2; kd[3]=nk3;
            u16* vd = st + pn*8960 + vw_u16;
            vd[(vd0+0)*34] = (u16)(nv0 & 0xffff); vd[(vd0+1)*34] = (u16)(nv0 >> 16);
            vd[(vd0+2)*34] = (u16)(nv1 & 0xffff); vd[(vd0+3)*34] = (u16)(nv1 >> 16);
            vd[(vd0+4)*34] = (u16)(nv2 & 0xffff); vd[(vd0+5)*34] = (u16)(nv2 >> 16);
            vd[(vd0+6)*34] = (u16)(nv3 & 0xffff); vd[(vd0+7)*34] = (u16)(nv3 >> 16);
        }
    }
    const float lacc = la0 + la1;

    __syncthreads();                  // staging dead; reuse LDS for combine
    float ltot = lacc + __shfl_xor(lacc, 32);
    float* ob = smemf + w * 1056;
#pragma unroll
    for (int r = 0; r < 16; ++r) {
        const int il = (r & 3) + 8*(r >> 2) + 4*hh;   // local query row
        ob[il*33 + l31] = oacc[r];                    // col = d = l31
    }
    if (lane < 32) smemf[8448 + w*32 + l31] = ltot;
    __syncthreads();

    if (tid < 128) {
        const int ii = tid >> 2, sub = tid & 3, d0 = sub * 8;
        float l1 = 0.f, l2 = 0.f;
#pragma unroll
        for (int q = 0; q < 4; ++q) {
            l1 += smemf[8448 + (2*q + 0)*32 + ii];
            l2 += smemf[8448 + (2*q + 1)*32 + ii];
        }

        float sA = 0.f, sB = 0.f;
#pragma unroll
        for (int d = 0; d < 16; ++d) {
            sA += lq1[d] * lk1[d];
            sB += lq2[d] * lk2[d];
        }
        const float lam = __expf(sA) - __expf(sB) + LAMBDA_INIT_F;
        const float c1 = 1.f / l1, c2 = lam / l2;

        float od[8]; float mu = 0.f;
#pragma unroll
        for (int dd = 0; dd < 8; ++dd) {
            const int d = d0 + dd;
            float o1 = 0.f, o2 = 0.f;
#pragma unroll
            for (int q = 0; q < 4; ++q) {
                o1 += smemf[(2*q + 0)*1056 + ii*33 + d];
                o2 += smemf[(2*q + 1)*1056 + ii*33 + d];
            }
            od[dd] = o1 * c1 - o2 * c2;
            mu += od[dd];
        }
        mu += __shfl_xor(mu, 1); mu += __shfl_xor(mu, 2);
        mu *= (1.f / 32.f);
        float var = 0.f;
#pragma unroll
        for (int dd = 0; dd < 8; ++dd) { const float t2 = od[dd] - mu; var += t2 * t2; }
        var += __shfl_xor(var, 1); var += __shfl_xor(var, 2);
        var *= (1.f / 32.f);
        const float rs = rsqrtf(var + 1e-5f);

        const int R = b*2048 + i0 + ii;
        const float* Gr = G + (size_t)R * 256 + ho*32 + d0;
        const float4 g0 = *(const float4*)(Gr);
        const float4 g1 = *(const float4*)(Gr + 4);
        const float gg[8] = { g0.x, g0.y, g0.z, g0.w, g1.x, g1.y, g1.z, g1.w };
        float vals[8];
#pragma unroll
        for (int dd = 0; dd < 8; ++dd) {
            const float val = (od[dd] - mu)*rs*gamma[d0 + dd] + beta[d0 + dd];
            vals[dd] = val * ONE_MINUS_LI * gg[dd];
        }
        u32x4 pk;
        pk[0] = pk2bf(vals[0], vals[1]);
        pk[1] = pk2bf(vals[2], vals[3]);
        pk[2] = pk2bf(vals[4], vals[5]);
        pk[3] = pk2bf(vals[6], vals[7]);
        *reinterpret_cast<u32x4*>(A + (size_t)R * 256 + ho*32 + d0) = pk;
    }
}

// ---------------------------------------------------------------------------
// Kernel 3: out = A(bf16) @ Wout + bout -> f32. Occupancy-raised: grid 1024
// (XCD-swizzled) x 256 thr; each block one 32x32 tile (mt 0..127, nt 0..7),
// 4 waves = 4-way K-split (64 each), LDS 4-sum combine.
// ---------------------------------------------------------------------------
__global__ __launch_bounds__(256) void out_kernel(
    const u16* __restrict__ Abf, const u16* __restrict__ WT,
    const float* __restrict__ bout, float* __restrict__ out)
{
    __shared__ float cs[4][32 * 33];

    const int bidl = xcd_swz1024(blockIdx.x);
    const int mt = bidl >> 3, nt = bidl & 7;
    const int tid = threadIdx.x, w = tid >> 6, lane = tid & 63;
    const int l31 = lane & 31, hh = lane >> 5;
    const int m0 = mt * 32;
    const int n0 = nt * 32;

    const u16* ar = Abf + (size_t)(m0 + l31) * 256 + w*64 + 8*hh;
    const u16* br = WT + (size_t)(1024 + n0 + l31) * 256 + w*64 + 8*hh;

    f16v acc;
#pragma unroll
    for (int r = 0; r < 16; ++r) acc[r] = 0.f;

#pragma unroll
    for (int ks = 0; ks < 4; ++ks) {
        s8v aa = *(const s8v*)(ar + ks*16);
        s8v ba = *(const s8v*)(br + ks*16);
        acc = MFMA16(aa, ba, acc);
    }

#pragma unroll
    for (int r = 0; r < 16; ++r) {
        const int il = (r & 3) + 8*(r >> 2) + 4*hh;
        cs[w][il*33 + l31] = acc[r];
    }
    __syncthreads();

#pragma unroll
    for (int e = 0; e < 4; ++e) {
        const int idx = tid + e*256;
        const int m = idx >> 5, nn = idx & 31;
        const float val = cs[0][m*33 + nn] + cs[1][m*33 + nn]
                        + cs[2][m*33 + nn] + cs[3][m*33 + nn] + bout[n0 + nn];
        out[(size_t)(m0 + m) * 256 + n0 + nn] = val;
    }
}

// ---------------------------------------------------------------------------
extern "C" void kernel_launch(void* const* d_in, const int* in_sizes, int n_in,
                              void* d_out, int out_size, void* d_ws, size_t ws_size,
                              hipStream_t stream) {
    const float* x    = (const float*)d_in[0];
    const float* Wq   = (const float*)d_in[1];
    const float* Wkv  = (const float*)d_in[2];
    const float* Wout = (const float*)d_in[3];
    const float* bout = (const float*)d_in[4];
    const float* Wg   = (const float*)d_in[5];
    const float* bg   = (const float*)d_in[6];
    const float* lq1  = (const float*)d_in[7];
    const float* lk1  = (const float*)d_in[8];
    const float* lq2  = (const float*)d_in[9];
    const float* lk2  = (const float*)d_in[10];
    const float* lng  = (const float*)d_in[11];
    const float* lnb  = (const float*)d_in[12];

    // ws: WT[1280*256] | xbf | Qb | Kb | Vb (u16) | Gb (f32) | Abf (u16)
    u16*   WT  = (u16*)d_ws;
    u16*   xbf = WT + 327680;
    u16*   Qb  = xbf + 1048576;
    u16*   Kb  = Qb + 1048576;
    u16*   Vb  = Kb + 1048576;
    float* Gb  = (float*)(Vb + 1048576);
    u16*   Abf = (u16*)(Gb + 1048576);

    hipLaunchKernelGGL(prep_kernel, dim3(144), dim3(256), 0, stream,
                       Wq, Wkv, Wg, Wout, x, WT, xbf);
    hipLaunchKernelGGL(proj_kernel, dim3(1024), dim3(256), 0, stream,
                       xbf, WT, bg, Qb, Kb, Vb, Gb);
    hipLaunchKernelGGL(attn_kernel, dim3(1024), dim3(512), 0, stream,
                       Qb, Kb, Vb, Gb, lq1, lk1, lq2, lk2, lng, lnb, Abf);
    hipLaunchKernelGGL(out_kernel, dim3(1024), dim3(256), 0, stream,
                       Abf, WT, bout, (float*)d_out);
}

// Round 8
// 141.877 us; speedup vs baseline: 1.5409x; 1.0040x over previous
//
#include <hip/hip_runtime.h>
#include <hip/hip_bf16.h>

#define LAMBDA_INIT_F 0.35550906759096927f
#define ONE_MINUS_LI  0.64449093240903073f
#define QSCALE 0.36067376022224085f   // 0.25 * log2(e): exp(s) == exp2(s_scaled)

typedef unsigned short u16;
typedef unsigned int   u32;
typedef short s8v  __attribute__((ext_vector_type(8)));
typedef u32   u32x4 __attribute__((ext_vector_type(4)));
typedef float f16v __attribute__((ext_vector_type(16)));

__device__ __forceinline__ u16 f2bf(float f) {
    __hip_bfloat16 h = __float2bfloat16(f);
    return *reinterpret_cast<u16*>(&h);
}
__device__ __forceinline__ u32 pk2bf(float lo, float hi) {
    return (u32)f2bf(lo) | ((u32)f2bf(hi) << 16);
}
union U4S8 { u32 u[4]; s8v s; };
__device__ __forceinline__ s8v mks8(u32 a, u32 b, u32 c, u32 d) {
    U4S8 x; x.u[0]=a; x.u[1]=b; x.u[2]=c; x.u[3]=d; return x.s;
}

// raw v_exp_f32 (1 inst) — libm exp2f is ~8 inst without -ffast-math
__device__ __forceinline__ float fexp2(float x) {
#if __has_builtin(__builtin_amdgcn_exp2f)
    return __builtin_amdgcn_exp2f(x);
#else
    float r; asm volatile("v_exp_f32 %0, %1\n\ts_nop 1" : "=v"(r) : "v"(x)); return r;
#endif
}

// gfx950 full-rate bf16 MFMA (K=16). C layout identical to 32x32x8_1k.
#define MFMA16(a,b,c) __builtin_amdgcn_mfma_f32_32x32x16_bf16((a),(b),(c),0,0,0)

// exchange halves across lane<32 / lane>=32
__device__ __forceinline__ void plswap2(u32& a, u32& b) {
    auto r = __builtin_amdgcn_permlane32_swap(a, b, false, false);
    a = r[0]; b = r[1];
}

// XCD-aware bijective swizzle for grid 1024 (8 XCDs, 128 blocks each):
// HW assigns bid%8 -> XCD; logical work L = (bid&7)*128 + bid>>3 gives each
// XCD a CONTIGUOUS logical range (2 (b,ho) head-combos -> ~1MB K/V in its L2).
// Counter-verified R7: attn cold FETCH 20MB -> 5.2MB.
__device__ __forceinline__ int xcd_swz1024(int bid) {
    return (bid & 7) * 128 + (bid >> 3);
}

// ---------------------------------------------------------------------------
// Kernel 0: prep. Blocks 0..79: transpose f32 weights -> bf16 WT[1280][256]
// (16 WT-rows per block). Blocks 80..143: x (f32) -> xbf (bf16), 64 rows each
// (float4 loads).
// ---------------------------------------------------------------------------
__global__ __launch_bounds__(256) void prep_kernel(
    const float* __restrict__ Wq, const float* __restrict__ Wkv,
    const float* __restrict__ Wg, const float* __restrict__ Wout,
    const float* __restrict__ x,
    u16* __restrict__ WT, u16* __restrict__ xbf)
{
    const int bid = blockIdx.x;
    const int tid = threadIdx.x;

    if (bid >= 80) {               // x convert: rows (bid-80)*64 .. +63
        const int r0 = (bid - 80) * 64;
        const float4* src = (const float4*)(x + (size_t)r0 * 256);
        u32* dst = (u32*)(xbf + (size_t)r0 * 256);
        for (int idx = tid; idx < 64 * 64; idx += 256) {
            float4 v = src[idx];
            dst[2*idx + 0] = pk2bf(v.x, v.y);
            dst[2*idx + 1] = pk2bf(v.z, v.w);
        }
        return;
    }

    __shared__ u16 tile[16 * 258];
    const int n0g = bid * 16;      // WT row base (0..1279)
    const float* src; int cols; int ncol0;
    if      (n0g < 256)  { src = Wq;   cols = 256; ncol0 = n0g; }
    else if (n0g < 768)  { src = Wkv;  cols = 512; ncol0 = n0g - 256; }
    else if (n0g < 1024) { src = Wg;   cols = 256; ncol0 = n0g - 768; }
    else                 { src = Wout; cols = 256; ncol0 = n0g - 1024; }

    const float* srow = src + (size_t)tid * cols + ncol0;
#pragma unroll
    for (int j = 0; j < 8; ++j) {
        const float2 v = *(const float2*)(srow + 2*j);
        tile[(2*j + 0) * 258 + tid] = f2bf(v.x);
        tile[(2*j + 1) * 258 + tid] = f2bf(v.y);
    }
    __syncthreads();

    const u32* t32 = (const u32*)tile;           // row stride 129 u32
    const int nn = tid >> 4, part = tid & 15;
    u32* dst = (u32*)WT + (size_t)(n0g + nn) * 128 + part * 8;
    const u32* s2 = t32 + nn * 129 + part * 8;
#pragma unroll
    for (int j = 0; j < 8; ++j) dst[j] = s2[j];
}

// ---------------------------------------------------------------------------
// Kernel 1: MFMA projections (R5 structure, no swizzle — R5 baseline proven).
// Grid 1024 = 64 mt x 16 nt, 256 thr, wave w -> (m-sub = w&1, n-sub = w>>1),
// 32x32 output per wave, full K=256.
// ---------------------------------------------------------------------------
__global__ __launch_bounds__(256) void proj_kernel(
    const u16* __restrict__ x, const u16* __restrict__ WT,
    const float* __restrict__ bg,
    u16* __restrict__ Qb, u16* __restrict__ Kb,
    u16* __restrict__ Vb, float* __restrict__ Gb)
{
    const int bid = blockIdx.x;
    const int nt = bid & 15, mt = bid >> 4;
    const int tid = threadIdx.x, w = tid >> 6, lane = tid & 63;
    const int l31 = lane & 31, hh = lane >> 5;
    const int ms = w & 1, nsub = w >> 1;
    const int m0 = mt * 64 + ms * 32;
    const int n0 = nt * 64 + nsub * 32;

    const u16* xr = x  + (size_t)(m0 + l31) * 256 + 8*hh;
    const u16* br = WT + (size_t)(n0 + l31) * 256 + 8*hh;

    f16v a0;
#pragma unroll
    for (int r = 0; r < 16; ++r) a0[r] = 0.f;

#pragma unroll
    for (int ks = 0; ks < 16; ++ks) {
        s8v xa = *(const s8v*)(xr + ks*16);
        s8v w0 = *(const s8v*)(br + ks*16);
        a0 = MFMA16(xa, w0, a0);
    }

    const int cat = nt >> 2;    // 0=Q 1=K 2=V 3=G
    const int n = n0 + l31;
#pragma unroll
    for (int r = 0; r < 16; ++r) {
        const int il = (r & 3) + 8*(r >> 2) + 4*hh;
        const int R = m0 + il;
        const int b = R >> 11, i = R & 2047;
        const float v = a0[r];
        if (cat == 0) {
            const int h = n >> 4, d = n & 15;
            Qb[((size_t)(b*16 + h) * 2048 + i) * 16 + d] = f2bf(v * QSCALE);
        } else if (cat == 1) {
            const int nk = n - 256, h = nk >> 4, d = nk & 15;
            Kb[((size_t)(b*16 + h) * 2048 + i) * 16 + d] = f2bf(v);
        } else if (cat == 2) {
            const int nv = n - 512, hv = nv >> 5, d2 = nv & 31;
            Vb[((size_t)(b*8 + hv) * 2048 + i) * 32 + d2] = f2bf(v);
        } else {
            const int gcol = n - 768;
            const float t = v + bg[gcol];
            Gb[(size_t)R * 256 + gcol] = 1.0f / (1.0f + __expf(-t));
        }
    }
}

// ---------------------------------------------------------------------------
// Kernel 2: MFMA flash differential attention + LN + gate -> bf16 A.
// R5 main-loop structure + XCD swizzle (counter-verified: FETCH 20->5.2MB)
// + combine tail widened 128 -> 512 threads (16 thr/row, 2 d each; mu/var
// via 4-step shfl_xor within the aligned 16-lane row group).
// ---------------------------------------------------------------------------
__global__ __launch_bounds__(512, 8) void attn_kernel(
    const u16* __restrict__ Q, const u16* __restrict__ K,
    const u16* __restrict__ V, const float* __restrict__ G,
    const float* __restrict__ lq1, const float* __restrict__ lk1,
    const float* __restrict__ lq2, const float* __restrict__ lk2,
    const float* __restrict__ gamma, const float* __restrict__ beta,
    u16* __restrict__ A)
{
    // staging: 2 buf x 4 slots x 1120 u32 = 8960 u32 = 35.8 KB
    // combine (reuse): 8 x (32x33 f32) O + 8x32 f32 l = 8704 f32
    __shared__ float smemf[8960];
    u16* st  = (u16*)smemf;
    u32* stu = (u32*)smemf;

    const int bidl = xcd_swz1024(blockIdx.x);
    const int itile = bidl & 63;
    const int combo = bidl >> 6;
    const int ho = combo & 7, b = combo >> 3;
    const int i0 = itile * 32;

    const int tid = threadIdx.x, w = tid >> 6, lane = tid & 63;
    const int l31 = lane & 31, hh = lane >> 5;
    const int s = w & 1, jq = w >> 1;

    const u16* Vg = V + (size_t)(b*8 + ho) * 2048 * 32;
    const u16* Qg = Q + ((size_t)(b*16 + 2*ho + s) * 2048 + (i0 + l31)) * 16;
    const s8v qf = *(const s8v*)(Qg + 8*hh);       // B-frag: col=query l31, k=8hh+e

    // --- staging assignment: wave-pair qp stages slot qp ---
    const int qp = tid >> 7;              // slot 0..3 (chunks qp*16 + t)
    const int pid = tid & 127;
    // K: 2 subheads x 32 rows x 8 u32; thread -> (ksub, krow, kseg): 4 u32
    const int ksub = pid >> 6, krow = (pid >> 1) & 31, kseg = pid & 1;
    const u32* kgp = (const u32*)(K + (size_t)(b*16 + 2*ho + ksub) * 2048 * 16)
                     + (size_t)qp * 4096 + krow * 8 + kseg * 4;
    // V: 32 rows(j) x 16 u32; thread -> (vj, vseg): 4 u32 = d vseg*8..+7
    const int vj = pid >> 2, vseg = pid & 3;
    const u32* vgp = (const u32*)Vg + (size_t)qp * 8192 + vj * 16 + vseg * 4;

    // LDS offsets: slot base qp*1120 u32 / qp*2240 u16; buffer +p*4480/+p*8960
    const int kw_off = qp*1120 + ksub*288 + krow*9 + kseg*4;   // u32 write
    const int vw_u16 = qp*2240 + 1152 + vj;                    // u16 write, +d*34
    const int vd0 = vseg * 8;
    const int kr_off = jq*1120 + s*288 + l31*9 + 4*hh;         // u32 read (k=8hh..+7)
    const int vr_off = jq*1120 + 576 + l31*17;                 // u32 read, +8f2+4hh

    f16v oacc;
#pragma unroll
    for (int r = 0; r < 16; ++r) oacc[r] = 0.f;
    float la0 = 0.f, la1 = 0.f;

    {   // prologue: stage round 0 into buffer 0
        u32 k0 = kgp[0], k1 = kgp[1], k2 = kgp[2], k3 = kgp[3];
        u32 v0 = vgp[0], v1 = vgp[1], v2 = vgp[2], v3 = vgp[3];
        u32* kd = stu + kw_off;
        kd[0]=k0; kd[1]=k1; kd[2]=k2; kd[3]=k3;
        u16* vd = st + vw_u16;
        vd[(vd0+0)*34] = (u16)(v0 & 0xffff); vd[(vd0+1)*34] = (u16)(v0 >> 16);
        vd[(vd0+2)*34] = (u16)(v1 & 0xffff); vd[(vd0+3)*34] = (u16)(v1 >> 16);
        vd[(vd0+4)*34] = (u16)(v2 & 0xffff); vd[(vd0+5)*34] = (u16)(v2 >> 16);
        vd[(vd0+6)*34] = (u16)(v3 & 0xffff); vd[(vd0+7)*34] = (u16)(v3 >> 16);
    }

    for (int t = 0; t < 16; ++t) {
        __syncthreads();
        const int p = t & 1, pn = 1 - p;
        const int tt = (t + 1) & 15;          // branchless wrap

        const u32* kp = kgp + (size_t)tt * 256;
        u32 nk0=kp[0], nk1=kp[1], nk2=kp[2], nk3=kp[3];
        const u32* vp = vgp + (size_t)tt * 512;
        u32 nv0=vp[0], nv1=vp[1], nv2=vp[2], nv3=vp[3];

        const u32* kb2 = stu + p*4480 + kr_off;
        const u32* vb2 = stu + p*4480 + vr_off;

        f16v sc;
#pragma unroll
        for (int r = 0; r < 16; ++r) sc[r] = 0.f;
        {
            s8v kf = mks8(kb2[0], kb2[1], kb2[2], kb2[3]);
            sc = MFMA16(kf, qf, sc);
        }
        float pv[16];
#pragma unroll
        for (int r = 0; r < 16; ++r) pv[r] = fexp2(sc[r]);
        la0 += pv[0];  la0 += pv[1];  la0 += pv[2];  la0 += pv[3];
        la1 += pv[4];  la1 += pv[5];  la1 += pv[6];  la1 += pv[7];
        la0 += pv[8];  la0 += pv[9];  la0 += pv[10]; la0 += pv[11];
        la1 += pv[12]; la1 += pv[13]; la1 += pv[14]; la1 += pv[15];

        // pack truncated bf16 pairs: w_i = keys (2i, 2i+1) + 4hh offset pattern
        u32 wv[8];
#pragma unroll
        for (int i = 0; i < 8; ++i)
            wv[i] = __builtin_amdgcn_perm(__float_as_uint(pv[2*i+1]),
                                          __float_as_uint(pv[2*i+0]), 0x07060302);
        // redistribute across wave halves for K=16 A-frags
        plswap2(wv[0], wv[2]); plswap2(wv[1], wv[3]);
        {
            s8v pf0 = mks8(wv[0], wv[1], wv[2], wv[3]);
            s8v vf0 = mks8(vb2[4*hh+0], vb2[4*hh+1], vb2[4*hh+2], vb2[4*hh+3]);
            oacc = MFMA16(pf0, vf0, oacc);
        }
        plswap2(wv[4], wv[6]); plswap2(wv[5], wv[7]);
        {
            s8v pf1 = mks8(wv[4], wv[5], wv[6], wv[7]);
            s8v vf1 = mks8(vb2[8+4*hh+0], vb2[8+4*hh+1], vb2[8+4*hh+2], vb2[8+4*hh+3]);
            oacc = MFMA16(pf1, vf1, oacc);
        }

        {   // stage round tt into buffer pn
            u32* kd = stu + pn*4480 + kw_off;
            kd[0]=nk0; kd[1]=nk1; kd[2]=nk2; kd[3]=nk3;
            u16* vd = st + pn*8960 + vw_u16;
            vd[(vd0+0)*34] = (u16)(nv0 & 0xffff); vd[(vd0+1)*34] = (u16)(nv0 >> 16);
            vd[(vd0+2)*34] = (u16)(nv1 & 0xffff); vd[(vd0+3)*34] = (u16)(nv1 >> 16);
            vd[(vd0+4)*34] = (u16)(nv2 & 0xffff); vd[(vd0+5)*34] = (u16)(nv2 >> 16);
            vd[(vd0+6)*34] = (u16)(nv3 & 0xffff); vd[(vd0+7)*34] = (u16)(nv3 >> 16);
        }
    }
    const float lacc = la0 + la1;

    __syncthreads();                  // staging dead; reuse LDS for combine
    float ltot = lacc + __shfl_xor(lacc, 32);
    float* ob = smemf + w * 1056;
#pragma unroll
    for (int r = 0; r < 16; ++r) {
        const int il = (r & 3) + 8*(r >> 2) + 4*hh;   // local query row
        ob[il*33 + l31] = oacc[r];                    // col = d = l31
    }
    if (lane < 32) smemf[8448 + w*32 + l31] = ltot;
    __syncthreads();

    {   // widened combine: all 512 threads; 16 per query row, 2 d each
        const int ii = tid >> 4, sub = tid & 15, d0 = sub * 2;
        float l1 = 0.f, l2 = 0.f;
#pragma unroll
        for (int q = 0; q < 4; ++q) {
            l1 += smemf[8448 + (2*q + 0)*32 + ii];
            l2 += smemf[8448 + (2*q + 1)*32 + ii];
        }

        float sA = 0.f, sB = 0.f;
#pragma unroll
        for (int d = 0; d < 16; ++d) {
            sA += lq1[d] * lk1[d];
            sB += lq2[d] * lk2[d];
        }
        const float lam = __expf(sA) - __expf(sB) + LAMBDA_INIT_F;
        const float c1 = 1.f / l1, c2 = lam / l2;

        float od[2]; float mu = 0.f;
#pragma unroll
        for (int dd = 0; dd < 2; ++dd) {
            const int d = d0 + dd;
            float o1 = 0.f, o2 = 0.f;
#pragma unroll
            for (int q = 0; q < 4; ++q) {
                o1 += smemf[(2*q + 0)*1056 + ii*33 + d];
                o2 += smemf[(2*q + 1)*1056 + ii*33 + d];
            }
            od[dd] = o1 * c1 - o2 * c2;
            mu += od[dd];
        }
        // row-reduce across the 16-lane group (lanes share ii: tid>>4)
        mu += __shfl_xor(mu, 1); mu += __shfl_xor(mu, 2);
        mu += __shfl_xor(mu, 4); mu += __shfl_xor(mu, 8);
        mu *= (1.f / 32.f);
        float var = 0.f;
#pragma unroll
        for (int dd = 0; dd < 2; ++dd) { const float t2 = od[dd] - mu; var += t2 * t2; }
        var += __shfl_xor(var, 1); var += __shfl_xor(var, 2);
        var += __shfl_xor(var, 4); var += __shfl_xor(var, 8);
        var *= (1.f / 32.f);
        const float rs = rsqrtf(var + 1e-5f);

        const int R = b*2048 + i0 + ii;
        const float2 gg = *(const float2*)(G + (size_t)R * 256 + ho*32 + d0);
        const float v0 = ((od[0] - mu)*rs*gamma[d0+0] + beta[d0+0]) * ONE_MINUS_LI * gg.x;
        const float v1 = ((od[1] - mu)*rs*gamma[d0+1] + beta[d0+1]) * ONE_MINUS_LI * gg.y;
        *reinterpret_cast<u32*>(A + (size_t)R * 256 + ho*32 + d0) = pk2bf(v0, v1);
    }
}

// ---------------------------------------------------------------------------
// Kernel 3: out = A(bf16) @ Wout + bout -> f32 (exact R5 version).
// Grid 256, 512 threads: 8 waves = 4 (32x32) tiles x 2 K-halves; LDS combine.
// ---------------------------------------------------------------------------
__global__ __launch_bounds__(512) void out_kernel(
    const u16* __restrict__ Abf, const u16* __restrict__ WT,
    const float* __restrict__ bout, float* __restrict__ out)
{
    __shared__ float cs[4][32 * 33];

    const int bid = blockIdx.x;
    const int nt = bid & 3, mt = bid >> 2;
    const int tid = threadIdx.x, w = tid >> 6, lane = tid & 63;
    const int l31 = lane & 31, hh = lane >> 5;
    const int t = w >> 1, kh = w & 1;
    const int m0 = mt * 64 + (t & 1) * 32;
    const int n0 = nt * 64 + (t >> 1) * 32;

    const u16* ar = Abf + (size_t)(m0 + l31) * 256 + kh*128 + 8*hh;
    const u16* br = WT + (size_t)(1024 + n0 + l31) * 256 + kh*128 + 8*hh;

    f16v acc;
#pragma unroll
    for (int r = 0; r < 16; ++r) acc[r] = 0.f;

#pragma unroll
    for (int ks = 0; ks < 8; ++ks) {
        s8v aa = *(const s8v*)(ar + ks*16);
        s8v ba = *(const s8v*)(br + ks*16);
        acc = MFMA16(aa, ba, acc);
    }

    if (kh == 0) {
#pragma unroll
        for (int r = 0; r < 16; ++r) {
            const int il = (r & 3) + 8*(r >> 2) + 4*hh;
            cs[t][il*33 + l31] = acc[r];
        }
    }
    __syncthreads();
    if (kh == 1) {
        const float bv = bout[n0 + l31];
#pragma unroll
        for (int r = 0; r < 16; ++r) {
            const int il = (r & 3) + 8*(r >> 2) + 4*hh;
            const int m = m0 + il;
            out[(size_t)m * 256 + n0 + l31] = acc[r] + cs[t][il*33 + l31] + bv;
        }
    }
}

// ---------------------------------------------------------------------------
extern "C" void kernel_launch(void* const* d_in, const int* in_sizes, int n_in,
                              void* d_out, int out_size, void* d_ws, size_t ws_size,
                              hipStream_t stream) {
    const float* x    = (const float*)d_in[0];
    const float* Wq   = (const float*)d_in[1];
    const float* Wkv  = (const float*)d_in[2];
    const float* Wout = (const float*)d_in[3];
    const float* bout = (const float*)d_in[4];
    const float* Wg   = (const float*)d_in[5];
    const float* bg   = (const float*)d_in[6];
    const float* lq1  = (const float*)d_in[7];
    const float* lk1  = (const float*)d_in[8];
    const float* lq2  = (const float*)d_in[9];
    const float* lk2  = (const float*)d_in[10];
    const float* lng  = (const float*)d_in[11];
    const float* lnb  = (const float*)d_in[12];

    // ws: WT[1280*256] | xbf | Qb | Kb | Vb (u16) | Gb (f32) | Abf (u16)
    u16*   WT  = (u16*)d_ws;
    u16*   xbf = WT + 327680;
    u16*   Qb  = xbf + 1048576;
    u16*   Kb  = Qb + 1048576;
    u16*   Vb  = Kb + 1048576;
    float* Gb  = (float*)(Vb + 1048576);
    u16*   Abf = (u16*)(Gb + 1048576);

    hipLaunchKernelGGL(prep_kernel, dim3(144), dim3(256), 0, stream,
                       Wq, Wkv, Wg, Wout, x, WT, xbf);
    hipLaunchKernelGGL(proj_kernel, dim3(1024), dim3(256), 0, stream,
                       xbf, WT, bg, Qb, Kb, Vb, Gb);
    hipLaunchKernelGGL(attn_kernel, dim3(1024), dim3(512), 0, stream,
                       Qb, Kb, Vb, Gb, lq1, lk1, lq2, lk2, lng, lnb, Abf);
    hipLaunchKernelGGL(out_kernel, dim3(256), dim3(512), 0, stream,
                       Abf, WT, bout, (float*)d_out);
}

// Round 9
// 139.085 us; speedup vs baseline: 1.5719x; 1.0201x over previous
//
#include <hip/hip_runtime.h>
#include <hip/hip_bf16.h>

#define LAMBDA_INIT_F 0.35550906759096927f
#define ONE_MINUS_LI  0.64449093240903073f
#define QSCALE 0.36067376022224085f   // 0.25 * log2(e): exp(s) == exp2(s_scaled)

typedef unsigned short u16;
typedef unsigned int   u32;
typedef short s8v  __attribute__((ext_vector_type(8)));
typedef u32   u32x4 __attribute__((ext_vector_type(4)));
typedef float f16v __attribute__((ext_vector_type(16)));

__device__ __forceinline__ u16 f2bf(float f) {
    __hip_bfloat16 h = __float2bfloat16(f);
    return *reinterpret_cast<u16*>(&h);
}
__device__ __forceinline__ u32 pk2bf(float lo, float hi) {
    return (u32)f2bf(lo) | ((u32)f2bf(hi) << 16);
}
union U4S8 { u32 u[4]; s8v s; };
__device__ __forceinline__ s8v mks8(u32 a, u32 b, u32 c, u32 d) {
    U4S8 x; x.u[0]=a; x.u[1]=b; x.u[2]=c; x.u[3]=d; return x.s;
}

// raw v_exp_f32 (1 inst) — libm exp2f is ~8 inst without -ffast-math
__device__ __forceinline__ float fexp2(float x) {
#if __has_builtin(__builtin_amdgcn_exp2f)
    return __builtin_amdgcn_exp2f(x);
#else
    float r; asm volatile("v_exp_f32 %0, %1\n\ts_nop 1" : "=v"(r) : "v"(x)); return r;
#endif
}

// gfx950 full-rate bf16 MFMA (K=16). C layout identical to 32x32x8_1k.
#define MFMA16(a,b,c) __builtin_amdgcn_mfma_f32_32x32x16_bf16((a),(b),(c),0,0,0)

// exchange halves across lane<32 / lane>=32
__device__ __forceinline__ void plswap2(u32& a, u32& b) {
    auto r = __builtin_amdgcn_permlane32_swap(a, b, false, false);
    a = r[0]; b = r[1];
}

// ---------------------------------------------------------------------------
// Kernel 0: prep. Blocks 0..79: transpose f32 weights -> bf16 WT[1280][256]
// (16 WT-rows per block). Blocks 80..143: x (f32) -> xbf (bf16), 64 rows each
// (float4 loads).
// ---------------------------------------------------------------------------
__global__ __launch_bounds__(256) void prep_kernel(
    const float* __restrict__ Wq, const float* __restrict__ Wkv,
    const float* __restrict__ Wg, const float* __restrict__ Wout,
    const float* __restrict__ x,
    u16* __restrict__ WT, u16* __restrict__ xbf)
{
    const int bid = blockIdx.x;
    const int tid = threadIdx.x;

    if (bid >= 80) {               // x convert: rows (bid-80)*64 .. +63
        const int r0 = (bid - 80) * 64;
        const float4* src = (const float4*)(x + (size_t)r0 * 256);
        u32* dst = (u32*)(xbf + (size_t)r0 * 256);
        for (int idx = tid; idx < 64 * 64; idx += 256) {
            float4 v = src[idx];
            dst[2*idx + 0] = pk2bf(v.x, v.y);
            dst[2*idx + 1] = pk2bf(v.z, v.w);
        }
        return;
    }

    __shared__ u16 tile[16 * 258];
    const int n0g = bid * 16;      // WT row base (0..1279)
    const float* src; int cols; int ncol0;
    if      (n0g < 256)  { src = Wq;   cols = 256; ncol0 = n0g; }
    else if (n0g < 768)  { src = Wkv;  cols = 512; ncol0 = n0g - 256; }
    else if (n0g < 1024) { src = Wg;   cols = 256; ncol0 = n0g - 768; }
    else                 { src = Wout; cols = 256; ncol0 = n0g - 1024; }

    const float* srow = src + (size_t)tid * cols + ncol0;
#pragma unroll
    for (int j = 0; j < 8; ++j) {
        const float2 v = *(const float2*)(srow + 2*j);
        tile[(2*j + 0) * 258 + tid] = f2bf(v.x);
        tile[(2*j + 1) * 258 + tid] = f2bf(v.y);
    }
    __syncthreads();

    const u32* t32 = (const u32*)tile;           // row stride 129 u32
    const int nn = tid >> 4, part = tid & 15;
    u32* dst = (u32*)WT + (size_t)(n0g + nn) * 128 + part * 8;
    const u32* s2 = t32 + nn * 129 + part * 8;
#pragma unroll
    for (int j = 0; j < 8; ++j) dst[j] = s2[j];
}

// ---------------------------------------------------------------------------
// Kernel 1: MFMA projections (exact R5). C[4096,1024] = xbf @ [Wq|Wk|Wv|Wg];
// grid 1024 = 64 mt x 16 nt, 256 thr, wave w -> (m-sub = w&1, n-sub = w>>1),
// 32x32 output per wave, full K=256.
// ---------------------------------------------------------------------------
__global__ __launch_bounds__(256) void proj_kernel(
    const u16* __restrict__ x, const u16* __restrict__ WT,
    const float* __restrict__ bg,
    u16* __restrict__ Qb, u16* __restrict__ Kb,
    u16* __restrict__ Vb, float* __restrict__ Gb)
{
    const int bid = blockIdx.x;
    const int nt = bid & 15, mt = bid >> 4;
    const int tid = threadIdx.x, w = tid >> 6, lane = tid & 63;
    const int l31 = lane & 31, hh = lane >> 5;
    const int ms = w & 1, nsub = w >> 1;
    const int m0 = mt * 64 + ms * 32;
    const int n0 = nt * 64 + nsub * 32;

    const u16* xr = x  + (size_t)(m0 + l31) * 256 + 8*hh;
    const u16* br = WT + (size_t)(n0 + l31) * 256 + 8*hh;

    f16v a0;
#pragma unroll
    for (int r = 0; r < 16; ++r) a0[r] = 0.f;

#pragma unroll
    for (int ks = 0; ks < 16; ++ks) {
        s8v xa = *(const s8v*)(xr + ks*16);
        s8v w0 = *(const s8v*)(br + ks*16);
        a0 = MFMA16(xa, w0, a0);
    }

    const int cat = nt >> 2;    // 0=Q 1=K 2=V 3=G
    const int n = n0 + l31;
#pragma unroll
    for (int r = 0; r < 16; ++r) {
        const int il = (r & 3) + 8*(r >> 2) + 4*hh;
        const int R = m0 + il;
        const int b = R >> 11, i = R & 2047;
        const float v = a0[r];
        if (cat == 0) {
            const int h = n >> 4, d = n & 15;
            Qb[((size_t)(b*16 + h) * 2048 + i) * 16 + d] = f2bf(v * QSCALE);
        } else if (cat == 1) {
            const int nk = n - 256, h = nk >> 4, d = nk & 15;
            Kb[((size_t)(b*16 + h) * 2048 + i) * 16 + d] = f2bf(v);
        } else if (cat == 2) {
            const int nv = n - 512, hv = nv >> 5, d2 = nv & 31;
            Vb[((size_t)(b*8 + hv) * 2048 + i) * 32 + d2] = f2bf(v);
        } else {
            const int gcol = n - 768;
            const float t = v + bg[gcol];
            Gb[(size_t)R * 256 + gcol] = 1.0f / (1.0f + __expf(-t));
        }
    }
}

// ---------------------------------------------------------------------------
// Kernel 2: MFMA flash differential attention + LN + gate -> bf16 A.
// R5 main loop verbatim (NO swizzle — R7/R8 showed it costs ~+2us steady-
// state: K/V is only 4MB so L2/L3 already hold it; concentrating a head on
// one XCD only unbalances load). Single change vs R5: combine tail widened
// 128 -> 512 threads (16 thr/row, 2 d each; mu/var via 4-step shfl_xor).
// ---------------------------------------------------------------------------
__global__ __launch_bounds__(512, 8) void attn_kernel(
    const u16* __restrict__ Q, const u16* __restrict__ K,
    const u16* __restrict__ V, const float* __restrict__ G,
    const float* __restrict__ lq1, const float* __restrict__ lk1,
    const float* __restrict__ lq2, const float* __restrict__ lk2,
    const float* __restrict__ gamma, const float* __restrict__ beta,
    u16* __restrict__ A)
{
    // staging: 2 buf x 4 slots x 1120 u32 = 8960 u32 = 35.8 KB
    // combine (reuse): 8 x (32x33 f32) O + 8x32 f32 l = 8704 f32
    __shared__ float smemf[8960];
    u16* st  = (u16*)smemf;
    u32* stu = (u32*)smemf;

    const int bid = blockIdx.x;
    const int itile = bid & 63;
    const int combo = bid >> 6;
    const int ho = combo & 7, b = combo >> 3;
    const int i0 = itile * 32;

    const int tid = threadIdx.x, w = tid >> 6, lane = tid & 63;
    const int l31 = lane & 31, hh = lane >> 5;
    const int s = w & 1, jq = w >> 1;

    const u16* Vg = V + (size_t)(b*8 + ho) * 2048 * 32;
    const u16* Qg = Q + ((size_t)(b*16 + 2*ho + s) * 2048 + (i0 + l31)) * 16;
    const s8v qf = *(const s8v*)(Qg + 8*hh);       // B-frag: col=query l31, k=8hh+e

    // --- staging assignment: wave-pair qp stages slot qp ---
    const int qp = tid >> 7;              // slot 0..3 (chunks qp*16 + t)
    const int pid = tid & 127;
    // K: 2 subheads x 32 rows x 8 u32; thread -> (ksub, krow, kseg): 4 u32
    const int ksub = pid >> 6, krow = (pid >> 1) & 31, kseg = pid & 1;
    const u32* kgp = (const u32*)(K + (size_t)(b*16 + 2*ho + ksub) * 2048 * 16)
                     + (size_t)qp * 4096 + krow * 8 + kseg * 4;
    // V: 32 rows(j) x 16 u32; thread -> (vj, vseg): 4 u32 = d vseg*8..+7
    const int vj = pid >> 2, vseg = pid & 3;
    const u32* vgp = (const u32*)Vg + (size_t)qp * 8192 + vj * 16 + vseg * 4;

    // LDS offsets: slot base qp*1120 u32 / qp*2240 u16; buffer +p*4480/+p*8960
    const int kw_off = qp*1120 + ksub*288 + krow*9 + kseg*4;   // u32 write
    const int vw_u16 = qp*2240 + 1152 + vj;                    // u16 write, +d*34
    const int vd0 = vseg * 8;
    const int kr_off = jq*1120 + s*288 + l31*9 + 4*hh;         // u32 read (k=8hh..+7)
    const int vr_off = jq*1120 + 576 + l31*17;                 // u32 read, +8f2+4hh

    f16v oacc;
#pragma unroll
    for (int r = 0; r < 16; ++r) oacc[r] = 0.f;
    float la0 = 0.f, la1 = 0.f;

    {   // prologue: stage round 0 into buffer 0
        u32 k0 = kgp[0], k1 = kgp[1], k2 = kgp[2], k3 = kgp[3];
        u32 v0 = vgp[0], v1 = vgp[1], v2 = vgp[2], v3 = vgp[3];
        u32* kd = stu + kw_off;
        kd[0]=k0; kd[1]=k1; kd[2]=k2; kd[3]=k3;
        u16* vd = st + vw_u16;
        vd[(vd0+0)*34] = (u16)(v0 & 0xffff); vd[(vd0+1)*34] = (u16)(v0 >> 16);
        vd[(vd0+2)*34] = (u16)(v1 & 0xffff); vd[(vd0+3)*34] = (u16)(v1 >> 16);
        vd[(vd0+4)*34] = (u16)(v2 & 0xffff); vd[(vd0+5)*34] = (u16)(v2 >> 16);
        vd[(vd0+6)*34] = (u16)(v3 & 0xffff); vd[(vd0+7)*34] = (u16)(v3 >> 16);
    }

    for (int t = 0; t < 16; ++t) {
        __syncthreads();
        const int p = t & 1, pn = 1 - p;
        const int tt = (t + 1) & 15;          // branchless wrap

        const u32* kp = kgp + (size_t)tt * 256;
        u32 nk0=kp[0], nk1=kp[1], nk2=kp[2], nk3=kp[3];
        const u32* vp = vgp + (size_t)tt * 512;
        u32 nv0=vp[0], nv1=vp[1], nv2=vp[2], nv3=vp[3];

        const u32* kb2 = stu + p*4480 + kr_off;
        const u32* vb2 = stu + p*4480 + vr_off;

        f16v sc;
#pragma unroll
        for (int r = 0; r < 16; ++r) sc[r] = 0.f;
        {
            s8v kf = mks8(kb2[0], kb2[1], kb2[2], kb2[3]);
            sc = MFMA16(kf, qf, sc);
        }
        float pv[16];
#pragma unroll
        for (int r = 0; r < 16; ++r) pv[r] = fexp2(sc[r]);
        la0 += pv[0];  la0 += pv[1];  la0 += pv[2];  la0 += pv[3];
        la1 += pv[4];  la1 += pv[5];  la1 += pv[6];  la1 += pv[7];
        la0 += pv[8];  la0 += pv[9];  la0 += pv[10]; la0 += pv[11];
        la1 += pv[12]; la1 += pv[13]; la1 += pv[14]; la1 += pv[15];

        // pack truncated bf16 pairs: w_i = keys (2i, 2i+1) + 4hh offset pattern
        u32 wv[8];
#pragma unroll
        for (int i = 0; i < 8; ++i)
            wv[i] = __builtin_amdgcn_perm(__float_as_uint(pv[2*i+1]),
                                          __float_as_uint(pv[2*i+0]), 0x07060302);
        // redistribute across wave halves for K=16 A-frags
        plswap2(wv[0], wv[2]); plswap2(wv[1], wv[3]);
        {
            s8v pf0 = mks8(wv[0], wv[1], wv[2], wv[3]);
            s8v vf0 = mks8(vb2[4*hh+0], vb2[4*hh+1], vb2[4*hh+2], vb2[4*hh+3]);
            oacc = MFMA16(pf0, vf0, oacc);
        }
        plswap2(wv[4], wv[6]); plswap2(wv[5], wv[7]);
        {
            s8v pf1 = mks8(wv[4], wv[5], wv[6], wv[7]);
            s8v vf1 = mks8(vb2[8+4*hh+0], vb2[8+4*hh+1], vb2[8+4*hh+2], vb2[8+4*hh+3]);
            oacc = MFMA16(pf1, vf1, oacc);
        }

        {   // stage round tt into buffer pn
            u32* kd = stu + pn*4480 + kw_off;
            kd[0]=nk0; kd[1]=nk1; kd[2]=nk2; kd[3]=nk3;
            u16* vd = st + pn*8960 + vw_u16;
            vd[(vd0+0)*34] = (u16)(nv0 & 0xffff); vd[(vd0+1)*34] = (u16)(nv0 >> 16);
            vd[(vd0+2)*34] = (u16)(nv1 & 0xffff); vd[(vd0+3)*34] = (u16)(nv1 >> 16);
            vd[(vd0+4)*34] = (u16)(nv2 & 0xffff); vd[(vd0+5)*34] = (u16)(nv2 >> 16);
            vd[(vd0+6)*34] = (u16)(nv3 & 0xffff); vd[(vd0+7)*34] = (u16)(nv3 >> 16);
        }
    }
    const float lacc = la0 + la1;

    __syncthreads();                  // staging dead; reuse LDS for combine
    float ltot = lacc + __shfl_xor(lacc, 32);
    float* ob = smemf + w * 1056;
#pragma unroll
    for (int r = 0; r < 16; ++r) {
        const int il = (r & 3) + 8*(r >> 2) + 4*hh;   // local query row
        ob[il*33 + l31] = oacc[r];                    // col = d = l31
    }
    if (lane < 32) smemf[8448 + w*32 + l31] = ltot;
    __syncthreads();

    {   // widened combine: all 512 threads; 16 per query row, 2 d each
        const int ii = tid >> 4, sub = tid & 15, d0 = sub * 2;
        float l1 = 0.f, l2 = 0.f;
#pragma unroll
        for (int q = 0; q < 4; ++q) {
            l1 += smemf[8448 + (2*q + 0)*32 + ii];
            l2 += smemf[8448 + (2*q + 1)*32 + ii];
        }

        float sA = 0.f, sB = 0.f;
#pragma unroll
        for (int d = 0; d < 16; ++d) {
            sA += lq1[d] * lk1[d];
            sB += lq2[d] * lk2[d];
        }
        const float lam = __expf(sA) - __expf(sB) + LAMBDA_INIT_F;
        const float c1 = 1.f / l1, c2 = lam / l2;

        float od[2]; float mu = 0.f;
#pragma unroll
        for (int dd = 0; dd < 2; ++dd) {
            const int d = d0 + dd;
            float o1 = 0.f, o2 = 0.f;
#pragma unroll
            for (int q = 0; q < 4; ++q) {
                o1 += smemf[(2*q + 0)*1056 + ii*33 + d];
                o2 += smemf[(2*q + 1)*1056 + ii*33 + d];
            }
            od[dd] = o1 * c1 - o2 * c2;
            mu += od[dd];
        }
        // row-reduce across the 16-lane group (lanes share ii = tid>>4)
        mu += __shfl_xor(mu, 1); mu += __shfl_xor(mu, 2);
        mu += __shfl_xor(mu, 4); mu += __shfl_xor(mu, 8);
        mu *= (1.f / 32.f);
        float var = 0.f;
#pragma unroll
        for (int dd = 0; dd < 2; ++dd) { const float t2 = od[dd] - mu; var += t2 * t2; }
        var += __shfl_xor(var, 1); var += __shfl_xor(var, 2);
        var += __shfl_xor(var, 4); var += __shfl_xor(var, 8);
        var *= (1.f / 32.f);
        const float rs = rsqrtf(var + 1e-5f);

        const int R = b*2048 + i0 + ii;
        const float2 gg = *(const float2*)(G + (size_t)R * 256 + ho*32 + d0);
        const float v0 = ((od[0] - mu)*rs*gamma[d0+0] + beta[d0+0]) * ONE_MINUS_LI * gg.x;
        const float v1 = ((od[1] - mu)*rs*gamma[d0+1] + beta[d0+1]) * ONE_MINUS_LI * gg.y;
        *reinterpret_cast<u32*>(A + (size_t)R * 256 + ho*32 + d0) = pk2bf(v0, v1);
    }
}

// ---------------------------------------------------------------------------
// Kernel 3: out = A(bf16) @ Wout + bout -> f32 (exact R5 version).
// Grid 256, 512 threads: 8 waves = 4 (32x32) tiles x 2 K-halves; LDS combine.
// ---------------------------------------------------------------------------
__global__ __launch_bounds__(512) void out_kernel(
    const u16* __restrict__ Abf, const u16* __restrict__ WT,
    const float* __restrict__ bout, float* __restrict__ out)
{
    __shared__ float cs[4][32 * 33];

    const int bid = blockIdx.x;
    const int nt = bid & 3, mt = bid >> 2;
    const int tid = threadIdx.x, w = tid >> 6, lane = tid & 63;
    const int l31 = lane & 31, hh = lane >> 5;
    const int t = w >> 1, kh = w & 1;
    const int m0 = mt * 64 + (t & 1) * 32;
    const int n0 = nt * 64 + (t >> 1) * 32;

    const u16* ar = Abf + (size_t)(m0 + l31) * 256 + kh*128 + 8*hh;
    const u16* br = WT + (size_t)(1024 + n0 + l31) * 256 + kh*128 + 8*hh;

    f16v acc;
#pragma unroll
    for (int r = 0; r < 16; ++r) acc[r] = 0.f;

#pragma unroll
    for (int ks = 0; ks < 8; ++ks) {
        s8v aa = *(const s8v*)(ar + ks*16);
        s8v ba = *(const s8v*)(br + ks*16);
        acc = MFMA16(aa, ba, acc);
    }

    if (kh == 0) {
#pragma unroll
        for (int r = 0; r < 16; ++r) {
            const int il = (r & 3) + 8*(r >> 2) + 4*hh;
            cs[t][il*33 + l31] = acc[r];
        }
    }
    __syncthreads();
    if (kh == 1) {
        const float bv = bout[n0 + l31];
#pragma unroll
        for (int r = 0; r < 16; ++r) {
            const int il = (r & 3) + 8*(r >> 2) + 4*hh;
            const int m = m0 + il;
            out[(size_t)m * 256 + n0 + l31] = acc[r] + cs[t][il*33 + l31] + bv;
        }
    }
}

// ---------------------------------------------------------------------------
extern "C" void kernel_launch(void* const* d_in, const int* in_sizes, int n_in,
                              void* d_out, int out_size, void* d_ws, size_t ws_size,
                              hipStream_t stream) {
    const float* x    = (const float*)d_in[0];
    const float* Wq   = (const float*)d_in[1];
    const float* Wkv  = (const float*)d_in[2];
    const float* Wout = (const float*)d_in[3];
    const float* bout = (const float*)d_in[4];
    const float* Wg   = (const float*)d_in[5];
    const float* bg   = (const float*)d_in[6];
    const float* lq1  = (const float*)d_in[7];
    const float* lk1  = (const float*)d_in[8];
    const float* lq2  = (const float*)d_in[9];
    const float* lk2  = (const float*)d_in[10];
    const float* lng  = (const float*)d_in[11];
    const float* lnb  = (const float*)d_in[12];

    // ws: WT[1280*256] | xbf | Qb | Kb | Vb (u16) | Gb (f32) | Abf (u16)
    u16*   WT  = (u16*)d_ws;
    u16*   xbf = WT + 327680;
    u16*   Qb  = xbf + 1048576;
    u16*   Kb  = Qb + 1048576;
    u16*   Vb  = Kb + 1048576;
    float* Gb  = (float*)(Vb + 1048576);
    u16*   Abf = (u16*)(Gb + 1048576);

    hipLaunchKernelGGL(prep_kernel, dim3(144), dim3(256), 0, stream,
                       Wq, Wkv, Wg, Wout, x, WT, xbf);
    hipLaunchKernelGGL(proj_kernel, dim3(1024), dim3(256), 0, stream,
                       xbf, WT, bg, Qb, Kb, Vb, Gb);
    hipLaunchKernelGGL(attn_kernel, dim3(1024), dim3(512), 0, stream,
                       Qb, Kb, Vb, Gb, lq1, lk1, lq2, lk2, lng, lnb, Abf);
    hipLaunchKernelGGL(out_kernel, dim3(256), dim3(512), 0, stream,
                       Abf, WT, bout, (float*)d_out);
}